// Round 5
// baseline (343.291 us; speedup 1.0000x reference)
//
#include <hip/hip_runtime.h>
#include <hip/hip_bf16.h>
#include <stdint.h>

#define E_N    200000
#define NODES  10000
#define GRAPHS 500
#define HID    256
#define K1RAW  581
#define K1P    640

typedef short bf16x8 __attribute__((ext_vector_type(8)));
typedef float f32x4  __attribute__((ext_vector_type(4)));

__device__ __forceinline__ short f2bf(float f){
  uint32_t u = __float_as_uint(f);
  u = (u + 0x7fffu + ((u >> 16) & 1u)) >> 16;
  return (short)u;
}
__device__ __forceinline__ float silu_f(float x){ return x / (1.f + __expf(-x)); }

// ---------------- prep: weight packing, bf16 convert, lattice IPs, counts ----------------
// Packed B layout for mfma_f32_16x16x32_bf16: Wp[((kb*16 + nb)*64 + lane)*8 + j]
// holds W[kb*32 + (lane>>4)*8 + j][nb*16 + (lane&15)], zero-padded for k >= K.
__device__ __forceinline__ void pack_one(const float* __restrict__ W, short* __restrict__ Wp,
                                         int K, int idx){
  int lane = idx & 63, t = idx >> 6;
  int nb = t & 15, kb = t >> 4;
  int n  = nb * 16 + (lane & 15);
  int k0 = kb * 32 + ((lane >> 4) << 3);
  bf16x8 v;
#pragma unroll
  for (int j = 0; j < 8; ++j){
    int k = k0 + j;
    v[j] = (k < K) ? f2bf(W[k * HID + n]) : (short)0;
  }
  ((bf16x8*)Wp)[idx] = v;
}

__global__ void prep_kernel(const float* __restrict__ We1, const float* __restrict__ We2,
                            const float* __restrict__ Wn1, const float* __restrict__ Wn2,
                            const float* __restrict__ nf, const float* __restrict__ lattices,
                            const int* __restrict__ ei,
                            short* We1p, short* We2p, short* Wn1p, short* Wn2p,
                            short* nfb, float* latw, float* cnt)
{
  int idx = blockIdx.x * 256 + threadIdx.x;
  if (idx < 20480){ pack_one(We1, We1p, K1RAW, idx); return; }   // K1P/32 * 16 * 64
  idx -= 20480;
  if (idx < 8192){ pack_one(We2, We2p, HID, idx); return; }
  idx -= 8192;
  if (idx < 16384){ pack_one(Wn1, Wn1p, 512, idx); return; }
  idx -= 16384;
  if (idx < 8192){ pack_one(Wn2, Wn2p, HID, idx); return; }
  idx -= 8192;
  if (idx < 320000){  // node features f32 -> bf16, 8 at a time
    const f32x4* p = (const f32x4*)(nf + (size_t)idx * 8);
    f32x4 a = p[0], b = p[1];
    bf16x8 v;
#pragma unroll
    for (int j = 0; j < 4; ++j){ v[j] = f2bf(a[j]); v[4+j] = f2bf(b[j]); }
    ((bf16x8*)nfb)[idx] = v;
    return;
  }
  idx -= 320000;
  if (idx < 4500){    // lat_ips[g][i][k] = dot(L[g,i,:], L[g,k,:])
    int g = idx / 9, r = idx % 9, i = r / 3, k = r % 3;
    const float* L = lattices + g * 9;
    latw[idx] = L[i*3+0]*L[k*3+0] + L[i*3+1]*L[k*3+1] + L[i*3+2]*L[k*3+2];
    return;
  }
  idx -= 4500;
  if (idx < E_N){     // per-source-node edge count
    atomicAdd(&cnt[ei[idx]], 1.f);
  }
}

// ---------------- edge MLP + scatter ----------------
// 512 threads = 8 waves. Block handles 64 edges x 256 out cols.
// Wave w owns cols [w*32, w*32+32). GEMM1 K padded 581->640 (10 chunks of 64).
__global__ __launch_bounds__(512) void edge_kernel(
    const int* __restrict__ ei, const float* __restrict__ fc,
    const float* __restrict__ latw, const int* __restrict__ e2g,
    const short* __restrict__ nfb,
    const short* __restrict__ We1p, const short* __restrict__ We2p,
    const float* __restrict__ be1, const float* __restrict__ be2,
    float* __restrict__ agg)
{
  __shared__ short A_s[64][72];     // K-chunk staging, stride 72 -> 2-way max conflict
  __shared__ short H1_s[64][264];   // silu(GEMM1) in bf16, stride 264
  __shared__ int   src_s[64];
  __shared__ int   dst_s[64];
  __shared__ float fd_s[64][3];
  __shared__ float lat_s[64][9];

  const int tid = threadIdx.x;
  const int e0  = blockIdx.x * 64;

  if (tid < 64){
    int e = e0 + tid;
    int s = ei[e], d = ei[E_N + e];
    src_s[tid] = s; dst_s[tid] = d;
    int g = e2g[e];
#pragma unroll
    for (int c = 0; c < 3; ++c){
      float df = fc[d*3+c] - fc[s*3+c];
      fd_s[tid][c] = df - floorf(df);          // jnp.mod(x, 1.0)
    }
#pragma unroll
    for (int j = 0; j < 9; ++j) lat_s[tid][j] = latw[g*9+j];
  }
  __syncthreads();

  const int lane = tid & 63;
  const int w    = tid >> 6;
  const int r    = tid >> 3;     // staging row
  const int cg   = tid & 7;      // staging col-group (8 bf16 each)
  const int arow = lane & 15;
  const int koff = (lane >> 4) << 3;
  const int rbase = (lane >> 4) << 2;
  const int colbase = w*32 + arow;

  const f32x4 zero4 = {0.f, 0.f, 0.f, 0.f};
  f32x4 acc[4][2];
#pragma unroll
  for (int i = 0; i < 4; ++i){ acc[i][0] = zero4; acc[i][1] = zero4; }

  // Build one 64-wide K chunk of e_in = [hi(256) | hj(256) | lat(9) | dis(60) | pad]
  auto stage_val = [&](int kc) -> bf16x8 {
    bf16x8 v;
    if (kc < 8){
      int node = (kc < 4) ? src_s[r] : dst_s[r];
      v = *(const bf16x8*)(nfb + (size_t)node * HID + (kc & 3) * 64 + cg * 8);
    } else {
#pragma unroll
      for (int j = 0; j < 8; ++j){
        int k = kc * 64 + cg * 8 + j;          // 512..639
        float val = 0.f;
        if (k < 521){
          val = lat_s[r][k - 512];
        } else if (k < 581){
          int m = k - 521;
          int mm = (m < 30) ? m : (m - 30);
          int coord = mm / 10, q = mm - coord * 10;
          float ang = 6.283185307179586f * (float)q * fd_s[r][coord];
          val = (m < 30) ? __sinf(ang) : __cosf(ang);
        }
        v[j] = f2bf(val);
      }
    }
    return v;
  };

  bf16x8 stg = stage_val(0);
#pragma unroll
  for (int kc = 0; kc < 10; ++kc){
    __syncthreads();                      // prior MFMA reads of A_s complete
    *(bf16x8*)&A_s[r][cg*8] = stg;
    if (kc < 9) stg = stage_val(kc + 1);  // prefetch overlaps MFMA phase
    __syncthreads();
#pragma unroll
    for (int sub = 0; sub < 2; ++sub){
      const int kb = kc*2 + sub;
      bf16x8 b0 = ((const bf16x8*)We1p)[(kb*16 + w*2 + 0)*64 + lane];
      bf16x8 b1 = ((const bf16x8*)We1p)[(kb*16 + w*2 + 1)*64 + lane];
#pragma unroll
      for (int rf = 0; rf < 4; ++rf){
        bf16x8 a = *(const bf16x8*)&A_s[rf*16 + arow][sub*32 + koff];
        acc[rf][0] = __builtin_amdgcn_mfma_f32_16x16x32_bf16(a, b0, acc[rf][0], 0, 0, 0);
        acc[rf][1] = __builtin_amdgcn_mfma_f32_16x16x32_bf16(a, b1, acc[rf][1], 0, 0, 0);
      }
    }
  }

  // epilogue 1: bias + silu -> bf16 into H1_s
  float b1c0 = be1[colbase], b1c1 = be1[colbase + 16];
#pragma unroll
  for (int rf = 0; rf < 4; ++rf){
#pragma unroll
    for (int j = 0; j < 4; ++j){
      int row = rf*16 + rbase + j;
      H1_s[row][colbase]      = f2bf(silu_f(acc[rf][0][j] + b1c0));
      H1_s[row][colbase + 16] = f2bf(silu_f(acc[rf][1][j] + b1c1));
    }
  }
  __syncthreads();

  // GEMM2: [64 x 256] @ We2
  f32x4 acc2[4][2];
#pragma unroll
  for (int i = 0; i < 4; ++i){ acc2[i][0] = zero4; acc2[i][1] = zero4; }
#pragma unroll
  for (int kb = 0; kb < 8; ++kb){
    bf16x8 b0 = ((const bf16x8*)We2p)[(kb*16 + w*2 + 0)*64 + lane];
    bf16x8 b1 = ((const bf16x8*)We2p)[(kb*16 + w*2 + 1)*64 + lane];
#pragma unroll
    for (int rf = 0; rf < 4; ++rf){
      bf16x8 a = *(const bf16x8*)&H1_s[rf*16 + arow][kb*32 + koff];
      acc2[rf][0] = __builtin_amdgcn_mfma_f32_16x16x32_bf16(a, b0, acc2[rf][0], 0, 0, 0);
      acc2[rf][1] = __builtin_amdgcn_mfma_f32_16x16x32_bf16(a, b1, acc2[rf][1], 0, 0, 0);
    }
  }

  // epilogue 2: bias + silu, scatter-add into agg[src]
  float b2c0 = be2[colbase], b2c1 = be2[colbase + 16];
#pragma unroll
  for (int rf = 0; rf < 4; ++rf){
#pragma unroll
    for (int j = 0; j < 4; ++j){
      int row = rf*16 + rbase + j;
      int s = src_s[row];
      atomicAdd(&agg[(size_t)s*HID + colbase],      silu_f(acc2[rf][0][j] + b2c0));
      atomicAdd(&agg[(size_t)s*HID + colbase + 16], silu_f(acc2[rf][1][j] + b2c1));
    }
  }
}

// ---------------- node MLP + residual ----------------
__global__ __launch_bounds__(512) void node_kernel(
    const short* __restrict__ nfb, const float* __restrict__ agg,
    const float* __restrict__ cnt,
    const short* __restrict__ Wn1p, const short* __restrict__ Wn2p,
    const float* __restrict__ bn1, const float* __restrict__ bn2,
    const float* __restrict__ nf, float* __restrict__ out)
{
  __shared__ short A_s[64][72];
  __shared__ short H1_s[64][264];
  __shared__ float rinv_s[64];

  const int tid = threadIdx.x;
  const int r0  = blockIdx.x * 64;
  if (tid < 64){
    int row = r0 + tid;
    float c = (row < NODES) ? cnt[row] : 1.f;
    rinv_s[tid] = 1.f / fmaxf(c, 1.f);
  }
  __syncthreads();

  const int lane = tid & 63;
  const int w    = tid >> 6;
  const int r    = tid >> 3;
  const int cg   = tid & 7;
  const int arow = lane & 15;
  const int koff = (lane >> 4) << 3;
  const int rbase = (lane >> 4) << 2;
  const int colbase = w*32 + arow;
  const int grow = min(r0 + r, NODES - 1);   // clamped gather row

  const f32x4 zero4 = {0.f, 0.f, 0.f, 0.f};
  f32x4 acc[4][2];
#pragma unroll
  for (int i = 0; i < 4; ++i){ acc[i][0] = zero4; acc[i][1] = zero4; }

  // n_in = [nf_bf16(256) | (agg/cnt)(256)]
  auto stage_val = [&](int kc) -> bf16x8 {
    bf16x8 v;
    if (kc < 4){
      v = *(const bf16x8*)(nfb + (size_t)grow * HID + kc*64 + cg*8);
    } else {
      const float* p = agg + (size_t)grow * HID + (kc - 4)*64 + cg*8;
      f32x4 a = *(const f32x4*)p, b = *(const f32x4*)(p + 4);
      float s = rinv_s[r];
#pragma unroll
      for (int j = 0; j < 4; ++j){ v[j] = f2bf(a[j]*s); v[4+j] = f2bf(b[j]*s); }
    }
    return v;
  };

  bf16x8 stg = stage_val(0);
#pragma unroll
  for (int kc = 0; kc < 8; ++kc){
    __syncthreads();
    *(bf16x8*)&A_s[r][cg*8] = stg;
    if (kc < 7) stg = stage_val(kc + 1);
    __syncthreads();
#pragma unroll
    for (int sub = 0; sub < 2; ++sub){
      const int kb = kc*2 + sub;
      bf16x8 b0 = ((const bf16x8*)Wn1p)[(kb*16 + w*2 + 0)*64 + lane];
      bf16x8 b1 = ((const bf16x8*)Wn1p)[(kb*16 + w*2 + 1)*64 + lane];
#pragma unroll
      for (int rf = 0; rf < 4; ++rf){
        bf16x8 a = *(const bf16x8*)&A_s[rf*16 + arow][sub*32 + koff];
        acc[rf][0] = __builtin_amdgcn_mfma_f32_16x16x32_bf16(a, b0, acc[rf][0], 0, 0, 0);
        acc[rf][1] = __builtin_amdgcn_mfma_f32_16x16x32_bf16(a, b1, acc[rf][1], 0, 0, 0);
      }
    }
  }

  float b1c0 = bn1[colbase], b1c1 = bn1[colbase + 16];
#pragma unroll
  for (int rf = 0; rf < 4; ++rf){
#pragma unroll
    for (int j = 0; j < 4; ++j){
      int row = rf*16 + rbase + j;
      H1_s[row][colbase]      = f2bf(silu_f(acc[rf][0][j] + b1c0));
      H1_s[row][colbase + 16] = f2bf(silu_f(acc[rf][1][j] + b1c1));
    }
  }
  __syncthreads();

  f32x4 acc2[4][2];
#pragma unroll
  for (int i = 0; i < 4; ++i){ acc2[i][0] = zero4; acc2[i][1] = zero4; }
#pragma unroll
  for (int kb = 0; kb < 8; ++kb){
    bf16x8 b0 = ((const bf16x8*)Wn2p)[(kb*16 + w*2 + 0)*64 + lane];
    bf16x8 b1 = ((const bf16x8*)Wn2p)[(kb*16 + w*2 + 1)*64 + lane];
#pragma unroll
    for (int rf = 0; rf < 4; ++rf){
      bf16x8 a = *(const bf16x8*)&H1_s[rf*16 + arow][kb*32 + koff];
      acc2[rf][0] = __builtin_amdgcn_mfma_f32_16x16x32_bf16(a, b0, acc2[rf][0], 0, 0, 0);
      acc2[rf][1] = __builtin_amdgcn_mfma_f32_16x16x32_bf16(a, b1, acc2[rf][1], 0, 0, 0);
    }
  }

  float b2c0 = bn2[colbase], b2c1 = bn2[colbase + 16];
#pragma unroll
  for (int rf = 0; rf < 4; ++rf){
#pragma unroll
    for (int j = 0; j < 4; ++j){
      int row = rf*16 + rbase + j;
      int grw = r0 + row;
      if (grw < NODES){
        size_t o0 = (size_t)grw * HID + colbase;
        out[o0]      = silu_f(acc2[rf][0][j] + b2c0) + nf[o0];
        out[o0 + 16] = silu_f(acc2[rf][1][j] + b2c1) + nf[o0 + 16];
      }
    }
  }
}

extern "C" void kernel_launch(void* const* d_in, const int* in_sizes, int n_in,
                              void* d_out, int out_size, void* d_ws, size_t ws_size,
                              hipStream_t stream) {
  const float* nf       = (const float*)d_in[0];
  const float* fc       = (const float*)d_in[1];
  const float* lattices = (const float*)d_in[2];
  const int*   ei       = (const int*)d_in[3];
  const int*   e2g      = (const int*)d_in[4];
  const float* We1      = (const float*)d_in[5];
  const float* be1      = (const float*)d_in[6];
  const float* We2      = (const float*)d_in[7];
  const float* be2      = (const float*)d_in[8];
  const float* Wn1      = (const float*)d_in[9];
  const float* bn1      = (const float*)d_in[10];
  const float* Wn2      = (const float*)d_in[11];
  const float* bn2      = (const float*)d_in[12];
  float* out = (float*)d_out;

  char* ws = (char*)d_ws;
  float* agg  = (float*)(ws);                  // 10,240,000 B
  float* cnt  = (float*)(ws + 10240000);       //     40,000 B
  short* nfb  = (short*)(ws + 10280000);       //  5,120,000 B
  float* latw = (float*)(ws + 15400000);       //     18,000 B
  short* We1p = (short*)(ws + 15418000);       //    327,680 B
  short* We2p = (short*)(ws + 15745680);       //    131,072 B
  short* Wn1p = (short*)(ws + 15876752);       //    262,144 B
  short* Wn2p = (short*)(ws + 16138896);       //    131,072 B  (end 16,269,968)

  // zero agg + cnt (ws is poisoned 0xAA before every timed call)
  hipMemsetAsync(ws, 0, 10280000, stream);

  prep_kernel<<<2257, 256, 0, stream>>>(We1, We2, Wn1, Wn2, nf, lattices, ei,
                                        We1p, We2p, Wn1p, Wn2p, nfb, latw, cnt);

  edge_kernel<<<E_N / 64, 512, 0, stream>>>(ei, fc, latw, e2g, nfb, We1p, We2p,
                                            be1, be2, agg);

  node_kernel<<<(NODES + 63) / 64, 512, 0, stream>>>(nfb, agg, cnt, Wn1p, Wn2p,
                                                     bn1, bn2, nf, out);
}